// Round 1
// baseline (7819.009 us; speedup 1.0000x reference)
//
#include <hip/hip_runtime.h>

#define B_ 512
#define T_ 256
#define F_ 8
#define H_ 128
#define BT_ (B_*T_)
#define MH_ 512

typedef __attribute__((ext_vector_type(4))) float f32x4;
typedef __attribute__((ext_vector_type(8))) __bf16 bf16x8;

// Static device scratch: W2 transposed to [n][k], bf16 bits. 512 KB.
__device__ unsigned short g_w2t[MH_*MH_];

__device__ __forceinline__ unsigned short f2bf(float f){
  unsigned int u = __float_as_uint(f);
  unsigned int r = (u + 0x7FFFu + ((u >> 16) & 1u)) >> 16;  // RNE
  return (unsigned short)r;
}

__device__ __forceinline__ float sigm(float x){
  x = fminf(fmaxf(x, -30.f), 30.f);
  return __builtin_amdgcn_rcpf(1.f + __expf(-x));
}
__device__ __forceinline__ float tanh_(float x){
  x = fminf(fmaxf(x, -15.f), 15.f);
  float e = __expf(2.f * x);
  return (e - 1.f) * __builtin_amdgcn_rcpf(e + 1.f);
}

__device__ __forceinline__ void acc2(float2& a, f32x4 w, f32x4 v){
  a.x = fmaf(w[0], v[0], a.x);
  a.y = fmaf(w[1], v[1], a.y);
  a.x = fmaf(w[2], v[2], a.x);
  a.y = fmaf(w[3], v[3], a.y);
}

struct LstmArgs {
  const float* x[3];
  const float* Wih[3];
  const float* Whh[3];
  const float* bias[3];
  const float* hw[3];
  const float* hb[3];
  float* out;
};

// One block = (head, 8-batch tile). 512 threads: thread (j = t&127, b2 = t>>7)
// owns gate rows {j, 128+j, 256+j, 384+j} (i,f,g,o for hidden unit j) and
// 2 batch elements. c stays in registers; h broadcast via LDS each step.
__global__ __launch_bounds__(512) void lstm_kernel(LstmArgs A){
  const int head   = blockIdx.x >> 6;     // 64 tiles per head
  const int batch0 = (blockIdx.x & 63) * 8;
  const float* __restrict__ xg  = A.x[head];
  const float* __restrict__ Wih = A.Wih[head];
  const float* __restrict__ Whh = A.Whh[head];
  const float* __restrict__ bs  = A.bias[head];
  const float* __restrict__ hwp = A.hw[head];
  const float hbv = A.hb[head][0];
  float* __restrict__ D = A.out + (size_t)head * BT_;

  __shared__ float hs[8 * H_];
  __shared__ float hwv[H_];

  const int t  = threadIdx.x;
  const int j  = t & 127;
  const int b2 = t >> 7;                  // 0..3 -> batches {2*b2, 2*b2+1}

  if (t < H_) hwv[t] = hwp[t];
  for (int i = t; i < 8 * H_; i += 512) hs[i] = 0.f;

  // Wih rows (8 floats each) for the 4 gates, register-resident
  f32x4 wi0 = *(const f32x4*)(Wih + j*8);            f32x4 wi1 = *(const f32x4*)(Wih + j*8 + 4);
  f32x4 wf0 = *(const f32x4*)(Wih + (H_+j)*8);       f32x4 wf1 = *(const f32x4*)(Wih + (H_+j)*8 + 4);
  f32x4 wg0 = *(const f32x4*)(Wih + (2*H_+j)*8);     f32x4 wg1 = *(const f32x4*)(Wih + (2*H_+j)*8 + 4);
  f32x4 wo0 = *(const f32x4*)(Wih + (3*H_+j)*8);     f32x4 wo1 = *(const f32x4*)(Wih + (3*H_+j)*8 + 4);
  const float bi_ = bs[j], bf_ = bs[H_+j], bg_ = bs[2*H_+j], bo_ = bs[3*H_+j];
  const float* __restrict__ wri = Whh + (size_t)j * H_;
  const float* __restrict__ wrf = Whh + (size_t)(H_   + j) * H_;
  const float* __restrict__ wrg = Whh + (size_t)(2*H_ + j) * H_;
  const float* __restrict__ wro = Whh + (size_t)(3*H_ + j) * H_;

  float c0 = 0.f, c1 = 0.f;
  __syncthreads();

  for (int ts = 0; ts < T_; ++ts){
    float2 zi[2], zf[2], zg[2], zo[2];
    #pragma unroll
    for (int q = 0; q < 2; ++q){
      zi[q].x = 0.f; zi[q].y = 0.f;  zf[q].x = 0.f; zf[q].y = 0.f;
      zg[q].x = 0.f; zg[q].y = 0.f;  zo[q].x = 0.f; zo[q].y = 0.f;
    }
    // input contribution: x_t @ Wih^T  (x read direct from global; L2-hot, broadcast)
    #pragma unroll
    for (int q = 0; q < 2; ++q){
      const float* xp = xg + (size_t)(batch0 + b2*2 + q) * (T_*F_) + ts*F_;
      f32x4 xa = *(const f32x4*)xp;
      f32x4 xb = *(const f32x4*)(xp + 4);
      acc2(zi[q], wi0, xa); acc2(zi[q], wi1, xb);
      acc2(zf[q], wf0, xa); acc2(zf[q], wf1, xb);
      acc2(zg[q], wg0, xa); acc2(zg[q], wg1, xb);
      acc2(zo[q], wo0, xa); acc2(zo[q], wo1, xb);
    }
    // recurrent contribution: h @ Whh^T
    #pragma unroll 4
    for (int k = 0; k < H_; k += 4){
      f32x4 wiv = *(const f32x4*)(wri + k);
      f32x4 wfv = *(const f32x4*)(wrf + k);
      f32x4 wgv = *(const f32x4*)(wrg + k);
      f32x4 wov = *(const f32x4*)(wro + k);
      #pragma unroll
      for (int q = 0; q < 2; ++q){
        f32x4 hv = *(const f32x4*)&hs[(b2*2 + q) * H_ + k];   // broadcast read
        acc2(zi[q], wiv, hv); acc2(zf[q], wfv, hv);
        acc2(zg[q], wgv, hv); acc2(zo[q], wov, hv);
      }
    }
    float hn0, hn1;
    {
      float Zi = zi[0].x + zi[0].y + bi_;
      float Zf = zf[0].x + zf[0].y + bf_;
      float Zg = zg[0].x + zg[0].y + bg_;
      float Zo = zo[0].x + zo[0].y + bo_;
      c0 = sigm(Zf) * c0 + sigm(Zi) * tanh_(Zg);
      hn0 = sigm(Zo) * tanh_(c0);
    }
    {
      float Zi = zi[1].x + zi[1].y + bi_;
      float Zf = zf[1].x + zf[1].y + bf_;
      float Zg = zg[1].x + zg[1].y + bg_;
      float Zo = zo[1].x + zo[1].y + bo_;
      c1 = sigm(Zf) * c1 + sigm(Zi) * tanh_(Zg);
      hn1 = sigm(Zo) * tanh_(c1);
    }
    __syncthreads();                       // all reads of old h done
    hs[(b2*2 + 0)*H_ + j] = hn0;
    hs[(b2*2 + 1)*H_ + j] = hn1;
    __syncthreads();                       // new h visible
    // D[b][ts] = h . hw + hb  (one 64-lane group per batch element)
    {
      const int bd = t >> 6;               // 0..7
      const int jj = t & 63;
      float2 h2 = *(const float2*)&hs[bd*H_ + jj*2];
      float2 w2 = *(const float2*)&hwv[jj*2];
      float p = h2.x*w2.x + h2.y*w2.y;
      p += __shfl_xor(p, 1);  p += __shfl_xor(p, 2);  p += __shfl_xor(p, 4);
      p += __shfl_xor(p, 8);  p += __shfl_xor(p, 16); p += __shfl_xor(p, 32);
      if (jj == 0) D[(size_t)(batch0 + bd) * T_ + ts] = p + hbv;
    }
  }
}

// W2 (k-major, f32) -> g_w2t (n-major, bf16)
__global__ __launch_bounds__(256) void prep_w2t(const float* __restrict__ W2){
  const int idx = blockIdx.x * 256 + threadIdx.x;   // = n*512 + k
  const int n = idx >> 9;
  const int k = idx & 511;
  g_w2t[idx] = f2bf(W2[(size_t)k * MH_ + n]);
}

// Fused MLP: h1 computed on the fly into A-fragments, h1@W2 via bf16 MFMA,
// relu+dot(W3) fused in epilogue. Block = 4 waves x 16 rows = 64 rows.
__global__ __launch_bounds__(256) void mlp_kernel(
    const float* __restrict__ Dbase,
    const float* __restrict__ W1, const float* __restrict__ b1,
    const float* __restrict__ b2, const float* __restrict__ W3,
    const float* __restrict__ b3, float* __restrict__ out)
{
  const int tid = threadIdx.x;
  const int l   = tid & 63;
  const int w   = tid >> 6;
  const int m0  = blockIdx.x * 64 + w * 16;
  const int c16 = l & 15;
  const int kb  = (l >> 4) * 8;

  const int gr = m0 + c16;                 // A-fragment row for this lane
  const float d1 = Dbase[gr];
  const float d2 = Dbase[BT_ + gr];
  const float d3 = Dbase[2*BT_ + gr];

  // A fragments: h1[row][k], lane holds k = ks*32 + kb + i (i=0..7)
  bf16x8 afr[16];
  #pragma unroll
  for (int ks = 0; ks < 16; ++ks){
    const int kg = ks*32 + kb;
    f32x4 wa0 = *(const f32x4*)(W1 + kg);          f32x4 wa1 = *(const f32x4*)(W1 + kg + 4);
    f32x4 wb0 = *(const f32x4*)(W1 + MH_ + kg);    f32x4 wb1 = *(const f32x4*)(W1 + MH_ + kg + 4);
    f32x4 wc0 = *(const f32x4*)(W1 + 2*MH_ + kg);  f32x4 wc1 = *(const f32x4*)(W1 + 2*MH_ + kg + 4);
    f32x4 bv0 = *(const f32x4*)(b1 + kg);          f32x4 bv1 = *(const f32x4*)(b1 + kg + 4);
    union { unsigned short u[8]; bf16x8 v; } au;
    #pragma unroll
    for (int i = 0; i < 4; ++i){
      float v0 = bv0[i] + d1*wa0[i] + d2*wb0[i] + d3*wc0[i];
      float v1 = bv1[i] + d1*wa1[i] + d2*wb1[i] + d3*wc1[i];
      au.u[i]     = f2bf(fmaxf(v0, 0.f));
      au.u[4 + i] = f2bf(fmaxf(v1, 0.f));
    }
    afr[ks] = au.v;
  }

  float rs[4] = {0.f, 0.f, 0.f, 0.f};      // per-lane partial row sums (4 C-rows)
  #pragma unroll 1
  for (int pass = 0; pass < 4; ++pass){    // N=512 in 4 passes of 128 cols
    f32x4 acc[8];
    #pragma unroll
    for (int tt = 0; tt < 8; ++tt){ f32x4 z = {0.f,0.f,0.f,0.f}; acc[tt] = z; }
    #pragma unroll
    for (int ks = 0; ks < 16; ++ks){
      #pragma unroll
      for (int tt = 0; tt < 8; ++tt){
        const int n = (pass*8 + tt)*16 + c16;
        const bf16x8 bfr = *(const bf16x8*)(g_w2t + (size_t)n * MH_ + ks*32 + kb);
        acc[tt] = __builtin_amdgcn_mfma_f32_16x16x32_bf16(afr[ks], bfr, acc[tt], 0, 0, 0);
      }
    }
    #pragma unroll
    for (int tt = 0; tt < 8; ++tt){
      const int n = (pass*8 + tt)*16 + c16;
      const float b2v = b2[n];
      const float w3v = W3[n];
      #pragma unroll
      for (int r = 0; r < 4; ++r)
        rs[r] += fmaxf(acc[tt][r] + b2v, 0.f) * w3v;
    }
  }
  // reduce across the 16 lanes (c16 bits) sharing the same C-rows
  #pragma unroll
  for (int r = 0; r < 4; ++r){
    rs[r] += __shfl_xor(rs[r], 1);
    rs[r] += __shfl_xor(rs[r], 2);
    rs[r] += __shfl_xor(rs[r], 4);
    rs[r] += __shfl_xor(rs[r], 8);
  }
  if (c16 == 0){
    const float bv = b3[0];
    const int row = m0 + (l >> 4) * 4;     // C layout: row = (l>>4)*4 + r
    #pragma unroll
    for (int r = 0; r < 4; ++r)
      out[3*BT_ + row + r] = rs[r] + bv;
  }
}

extern "C" void kernel_launch(void* const* d_in, const int* in_sizes, int n_in,
                              void* d_out, int out_size, void* d_ws, size_t ws_size,
                              hipStream_t stream){
  LstmArgs A;
  for (int i = 0; i < 3; ++i){
    A.x[i]    = (const float*)d_in[i];
    A.Wih[i]  = (const float*)d_in[3 + i*5 + 0];
    A.Whh[i]  = (const float*)d_in[3 + i*5 + 1];
    A.bias[i] = (const float*)d_in[3 + i*5 + 2];
    A.hw[i]   = (const float*)d_in[3 + i*5 + 3];
    A.hb[i]   = (const float*)d_in[3 + i*5 + 4];
  }
  A.out = (float*)d_out;

  prep_w2t<<<dim3(1024), dim3(256), 0, stream>>>((const float*)d_in[20]);
  lstm_kernel<<<dim3(192), dim3(512), 0, stream>>>(A);
  mlp_kernel<<<dim3(2048), dim3(256), 0, stream>>>((const float*)d_out,
      (const float*)d_in[18], (const float*)d_in[19],
      (const float*)d_in[21], (const float*)d_in[22], (const float*)d_in[23],
      (float*)d_out);
}